// Round 2
// baseline (100316.748 us; speedup 1.0000x reference)
//
#include <hip/hip_runtime.h>
#include <hip/hip_bf16.h>
#include <hip/hip_cooperative_groups.h>

namespace cg = cooperative_groups;

// Problem constants
constexpr int B_   = 32;
constexpr int S_   = 512;
constexpr int T_   = 512;
constexpr int ENC_ = 512;
constexpr int ATT_ = 128;
constexpr int PO_  = 256;
constexpr int DEC_ = 1024;
constexpr int M_   = 128;
constexpr int G3_  = 3072;   // 3*DEC

// Output offsets (floats)
constexpr int MEL_OFF  = 0;
constexpr int STOP_OFF = B_*T_*M_;            // 2,097,152
constexpr int AW_OFF   = STOP_OFF + B_*T_;    // 2,113,536

__device__ __forceinline__ float frcp(float x){ return __builtin_amdgcn_rcpf(x); }
__device__ __forceinline__ float ftanh(float x){
    float e = __expf(2.0f*x);               // +inf / 0 saturate correctly
    return 1.0f - 2.0f*frcp(e + 1.0f);
}
__device__ __forceinline__ float fsig(float x){ return frcp(1.0f + __expf(-x)); }

// ---------------- prep: swizzled weight slabs ---------------------------------
// whh_s[g][1024][16]  g<192 : whh[(g*16+j)][k]          (whh is [3072][1024])
// wix_s[g][256][16]   g<192 : wih[(g*16+j)][k], k<256   (wih is [3072][768])
// wic_s[z][512][12]   z<256 : wih[(jj>>2)*1024+z*4+(jj&3)][256+e]
// wd_s [i][1024][8]   i<16  : awd[k][i*8+j]             (awd is [1024][128])
// ow_s [i][1536][8]   i<16  : oww[k][i*8+j]             (oww is [1536][128])
__global__ __launch_bounds__(256) void k_prep(const float* __restrict__ whh,
        const float* __restrict__ wih, const float* __restrict__ awd,
        const float* __restrict__ oww,
        float* __restrict__ whh_s, float* __restrict__ wix_s,
        float* __restrict__ wic_s, float* __restrict__ wd_s,
        float* __restrict__ ow_s){
    long long idx = (long long)blockIdx.x*256 + threadIdx.x;
    if (idx < 3145728LL){
        int g = (int)(idx >> 14); int r = (int)(idx & 16383);
        int k = r >> 4, j = r & 15;
        whh_s[idx] = whh[(size_t)(g*16 + j)*1024 + k];
    } else if (idx < 3932160LL){
        long long q = idx - 3145728LL;
        int g = (int)(q >> 12); int r = (int)(q & 4095);
        int k = r >> 4, j = r & 15;
        wix_s[q] = wih[(size_t)(g*16 + j)*768 + k];
    } else if (idx < 5505024LL){
        long long q = idx - 3932160LL;
        int z = (int)(q / 6144); int r = (int)(q % 6144);
        int e = r / 12, jj = r % 12;
        int c = (jj >> 2)*1024 + z*4 + (jj & 3);
        wic_s[q] = wih[(size_t)c*768 + 256 + e];
    } else if (idx < 5636096LL){
        long long q = idx - 5505024LL;
        int i = (int)(q >> 13); int r = (int)(q & 8191);
        int k = r >> 3, j = r & 7;
        wd_s[q] = awd[(size_t)k*128 + i*8 + j];
    } else if (idx < 5832704LL){
        long long q = idx - 5636096LL;
        int i = (int)(q / 12288); int r = (int)(q % 12288);
        int k = r >> 3, j = r & 7;
        ow_s[q] = oww[(size_t)k*128 + i*8 + j];
    }
}

// ---------------- prep: ep[b][a][s] = bf16(enc @ att_we + be) -----------------
__global__ __launch_bounds__(128) void k_encproj(const float* __restrict__ enc,
        const float* __restrict__ we, const float* __restrict__ be,
        __hip_bfloat16* __restrict__ ep_t){
    __shared__ float wel[64*128];
    __shared__ float encl[32*69];
    int b = blockIdx.x >> 4, s0 = (blockIdx.x & 15) << 5;
    int tid = threadIdx.x;
    int sl = tid & 31, ag = tid >> 5;        // ag 0..3 -> 32 a's each
    float acc[32];
    #pragma unroll
    for (int i = 0; i < 32; i++) acc[i] = 0.f;
    for (int k0 = 0; k0 < ENC_; k0 += 64){
        __syncthreads();
        for (int p = 0; p < 64; p++){
            int idx = tid + (p << 7);
            wel[idx] = we[(size_t)(k0 + (idx >> 7))*ATT_ + (idx & 127)];
        }
        for (int p = 0; p < 16; p++){
            int idx = tid + (p << 7);
            int kk = idx & 63, ss = idx >> 6;
            encl[ss*69 + kk] = enc[((size_t)b*S_ + s0 + ss)*ENC_ + k0 + kk];
        }
        __syncthreads();
        for (int kk = 0; kk < 64; kk++){
            float ev = encl[sl*69 + kk];
            const float* wr = &wel[(kk << 7) + (ag << 5)];
            #pragma unroll
            for (int j = 0; j < 32; j++) acc[j] += ev * wr[j];
        }
    }
    #pragma unroll
    for (int j = 0; j < 32; j++){
        int a = (ag << 5) + j;
        ep_t[((size_t)b*ATT_ + a)*S_ + s0 + sl] = __float2bfloat16(acc[j] + be[a]);
    }
}

// ---------------- prep: X_all[t][b][:] = PreNet(prev_mel) ---------------------
__global__ __launch_bounds__(128) void k_prenet(const float* __restrict__ tm,
        const float* __restrict__ w1, const float* __restrict__ b1,
        const float* __restrict__ w2, const float* __restrict__ b2,
        float* __restrict__ xall){
    __shared__ float mel_l[128*20];
    __shared__ float h1_l[256*20];
    int row0 = blockIdx.x << 4;              // 16 rows per block, same t
    int t = row0 >> 5, b0 = row0 & 31;
    int tid = threadIdx.x;
    for (int p = 0; p < 16; p++){
        int idx = tid + (p << 7);
        int k = idx & 127, r = idx >> 7;
        float v = 0.f;
        if (t > 0) v = tm[((size_t)(b0 + r)*T_ + (t - 1))*M_ + k];
        mel_l[k*20 + r] = v;
    }
    __syncthreads();
    float acc1[16], acc2[16];
    #pragma unroll
    for (int i = 0; i < 16; i++){ acc1[i] = 0.f; acc2[i] = 0.f; }
    for (int k = 0; k < M_; k++){
        float wa = w1[k*256 + tid];
        float wb = w1[k*256 + tid + 128];
        float mv[16];
        *(float4*)&mv[0]  = *(const float4*)&mel_l[k*20 + 0];
        *(float4*)&mv[4]  = *(const float4*)&mel_l[k*20 + 4];
        *(float4*)&mv[8]  = *(const float4*)&mel_l[k*20 + 8];
        *(float4*)&mv[12] = *(const float4*)&mel_l[k*20 + 12];
        #pragma unroll
        for (int r = 0; r < 16; r++){ acc1[r] += mv[r]*wa; acc2[r] += mv[r]*wb; }
    }
    float bb1a = b1[tid], bb1b = b1[tid + 128];
    #pragma unroll
    for (int r = 0; r < 16; r++){
        h1_l[tid*20 + r]         = fmaxf(acc1[r] + bb1a, 0.f);
        h1_l[(tid + 128)*20 + r] = fmaxf(acc2[r] + bb1b, 0.f);
    }
    __syncthreads();
    #pragma unroll
    for (int i = 0; i < 16; i++){ acc1[i] = 0.f; acc2[i] = 0.f; }
    for (int k = 0; k < 256; k++){
        float wa = w2[k*256 + tid];
        float wb = w2[k*256 + tid + 128];
        float mv[16];
        *(float4*)&mv[0]  = *(const float4*)&h1_l[k*20 + 0];
        *(float4*)&mv[4]  = *(const float4*)&h1_l[k*20 + 4];
        *(float4*)&mv[8]  = *(const float4*)&h1_l[k*20 + 8];
        *(float4*)&mv[12] = *(const float4*)&h1_l[k*20 + 12];
        #pragma unroll
        for (int r = 0; r < 16; r++){ acc1[r] += mv[r]*wa; acc2[r] += mv[r]*wb; }
    }
    float bb2a = b2[tid], bb2b = b2[tid + 128];
    #pragma unroll
    for (int r = 0; r < 16; r++){
        xall[((size_t)row0 + r)*PO_ + tid]       = fmaxf(acc1[r] + bb2a, 0.f);
        xall[((size_t)row0 + r)*PO_ + tid + 128] = fmaxf(acc2[r] + bb2b, 0.f);
    }
}

// ---------------- the persistent decoder loop ---------------------------------
// 256 blocks x 1024 threads, cooperative. 3 grid syncs per step.
__global__ __launch_bounds__(1024, 4) void k_persist(
    const float* __restrict__ enc,        // [32][512][512]
    const float* __restrict__ xall,       // [T*32][256]
    const __hip_bfloat16* __restrict__ ep,// [32][128][512]
    const float* __restrict__ whh_s,      // [192][1024][16]
    const float* __restrict__ wix_s,      // [192][256][16]
    const float* __restrict__ wic_s,      // [256][512][12]
    const float* __restrict__ wd_s,       // [16][1024][8]
    const float* __restrict__ ow_s,       // [16][1536][8]
    const float* __restrict__ sw,         // [1536]
    const float* __restrict__ bd,         // [128]
    const float* __restrict__ av,         // [128]
    const float* __restrict__ avb,        // [1]
    const float* __restrict__ bih,        // [3072]
    const float* __restrict__ bhh,        // [3072]
    const float* __restrict__ ob,         // [128]
    const float* __restrict__ sb,         // [1]
    float* __restrict__ hbuf,             // [2][32][1024]
    float* __restrict__ ghb,              // [32][3072]
    float* __restrict__ gixb,             // [32][3072]
    float* __restrict__ dproj,            // [32][128]  (includes +bd)
    float* __restrict__ esb,              // [32][512]
    float* __restrict__ denp,             // [2][32]
    float* __restrict__ ctxp,             // [2][32][512] (unnormalized)
    float* __restrict__ out)
{
    cg::grid_group grid = cg::this_grid();
    __shared__ float smem[1664];
    const int bid = blockIdx.x, tid = threadIdx.x;

    for (int t = 0; t <= T_; ++t){
        const float* hp = hbuf + (size_t)(t & 1)*(B_*DEC_);
        float*       hn = hbuf + (size_t)((t & 1) ^ 1)*(B_*DEC_);

        // ================= PHASE X =================
        if (bid < 192){
            // gh = h_{t-1} @ Whh^T  and  gix = x_t @ Wix^T, 16 cols each
            if (t < T_){
                const int b = tid >> 5, kl = tid & 31;
                const float* hr = hp + b*DEC_;
                const float* xr = xall + ((size_t)t*B_ + b)*PO_;
                const float* wX = wix_s + (size_t)bid*(256*16);
                const float* wH = whh_s + (size_t)bid*(1024*16);
                float agh[16], agx[16];
                #pragma unroll
                for (int j = 0; j < 16; ++j){ agh[j] = 0.f; agx[j] = 0.f; }
                for (int q = 0; q < 8; ++q){
                    int k = q*32 + kl;
                    float xv = xr[k];
                    const float* w = wX + k*16;
                    #pragma unroll
                    for (int j = 0; j < 16; j += 4){
                        float4 wv = *(const float4*)(w + j);
                        agx[j]   += xv*wv.x; agx[j+1] += xv*wv.y;
                        agx[j+2] += xv*wv.z; agx[j+3] += xv*wv.w;
                    }
                }
                for (int q = 0; q < 32; ++q){
                    int k = q*32 + kl;
                    float hv = hr[k];
                    const float* w = wH + k*16;
                    #pragma unroll
                    for (int j = 0; j < 16; j += 4){
                        float4 wv = *(const float4*)(w + j);
                        agh[j]   += hv*wv.x; agh[j+1] += hv*wv.y;
                        agh[j+2] += hv*wv.z; agh[j+3] += hv*wv.w;
                    }
                }
                #pragma unroll
                for (int m = 1; m <= 16; m <<= 1){
                    #pragma unroll
                    for (int j = 0; j < 16; ++j){
                        agh[j] += __shfl_xor(agh[j], m);
                        agx[j] += __shfl_xor(agx[j], m);
                    }
                }
                if (kl == 0){
                    float* go = ghb  + b*G3_ + bid*16;
                    float* xo = gixb + b*G3_ + bid*16;
                    #pragma unroll
                    for (int j = 0; j < 16; ++j){ go[j] = agh[j]; xo[j] = agx[j]; }
                }
            }
        } else if (bid < 208){
            // dproj = h_{t-1} @ Wd + bd, 8 a-cols
            if (t < T_){
                const int i = bid - 192;
                const int b = tid >> 5, kl = tid & 31;
                const float* hr = hp + b*DEC_;
                const float* wD = wd_s + (size_t)i*(1024*8);
                float acc[8];
                #pragma unroll
                for (int j = 0; j < 8; ++j) acc[j] = 0.f;
                for (int q = 0; q < 32; ++q){
                    int k = q*32 + kl;
                    float hv = hr[k];
                    const float* w = wD + k*8;
                    #pragma unroll
                    for (int j = 0; j < 8; j += 4){
                        float4 wv = *(const float4*)(w + j);
                        acc[j]   += hv*wv.x; acc[j+1] += hv*wv.y;
                        acc[j+2] += hv*wv.z; acc[j+3] += hv*wv.w;
                    }
                }
                #pragma unroll
                for (int m = 1; m <= 16; m <<= 1){
                    #pragma unroll
                    for (int j = 0; j < 8; ++j) acc[j] += __shfl_xor(acc[j], m);
                }
                if (kl == 0){
                    #pragma unroll
                    for (int j = 0; j < 8; ++j)
                        dproj[b*ATT_ + i*8 + j] = acc[j] + bd[i*8 + j];
                }
            }
        } else if (bid < 224){
            // mel/stop for step t-1 (dout = [h_{t-1}, ctx_{t-1}]), 8 mel cols
            if (t > 0){
                const int i = bid - 208;
                const int b = tid >> 5, kl = tid & 31;
                const float* hr = hp + b*DEC_;
                const float rden = frcp(denp[b] + denp[32 + b]);
                const float* wO = ow_s + (size_t)i*(1536*8);
                float acc[8];
                #pragma unroll
                for (int j = 0; j < 8; ++j) acc[j] = 0.f;
                float sacc = 0.f;
                for (int q = 0; q < 32; ++q){
                    int k = q*32 + kl;
                    float dv = hr[k];
                    const float* w = wO + k*8;
                    #pragma unroll
                    for (int j = 0; j < 8; j += 4){
                        float4 wv = *(const float4*)(w + j);
                        acc[j]   += dv*wv.x; acc[j+1] += dv*wv.y;
                        acc[j+2] += dv*wv.z; acc[j+3] += dv*wv.w;
                    }
                    if (i == 15) sacc += dv*sw[k];
                }
                for (int q = 0; q < 16; ++q){
                    int e = q*32 + kl;
                    int k = 1024 + e;
                    float dv = (ctxp[b*ENC_ + e] + ctxp[16384 + b*ENC_ + e])*rden;
                    const float* w = wO + k*8;
                    #pragma unroll
                    for (int j = 0; j < 8; j += 4){
                        float4 wv = *(const float4*)(w + j);
                        acc[j]   += dv*wv.x; acc[j+1] += dv*wv.y;
                        acc[j+2] += dv*wv.z; acc[j+3] += dv*wv.w;
                    }
                    if (i == 15) sacc += dv*sw[k];
                }
                #pragma unroll
                for (int m = 1; m <= 16; m <<= 1){
                    #pragma unroll
                    for (int j = 0; j < 8; ++j) acc[j] += __shfl_xor(acc[j], m);
                    if (i == 15) sacc += __shfl_xor(sacc, m);
                }
                if (kl == 0){
                    float* mo = out + MEL_OFF + ((size_t)b*T_ + (t - 1))*M_ + i*8;
                    #pragma unroll
                    for (int j = 0; j < 8; ++j) mo[j] = acc[j] + ob[i*8 + j];
                    if (i == 15) out[STOP_OFF + b*T_ + (t - 1)] = sacc + sb[0];
                }
            }
        }
        if (t == T_) break;
        grid.sync();

        // ================= PHASE Y =================
        {
            const int b = bid >> 3, sp = (bid >> 2) & 1, eq = bid & 3;
            float* red  = smem;          // [1024]
            float* es_l = smem + 1024;   // [256]
            float* dpl  = smem + 1280;   // [128]
            float* vl   = smem + 1408;   // [128]
            if (tid < 128){ dpl[tid] = dproj[b*ATT_ + tid]; vl[tid] = av[tid]; }
            __syncthreads();
            // scores (redundant across eq) for 256 s
            const int ag = tid >> 8, sl = tid & 255;
            const int sg = sp*256 + sl;
            const __hip_bfloat16* epb = ep + ((size_t)(b*ATT_ + ag*32))*S_ + sg;
            float acc = 0.f;
            #pragma unroll 4
            for (int aa = 0; aa < 32; ++aa){
                float e = __bfloat162float(epb[(size_t)aa*S_]);
                int a = ag*32 + aa;
                acc += ftanh(e + dpl[a]) * vl[a];
            }
            red[tid] = acc;
            __syncthreads();
            if (tid < 256){
                float sc = red[tid] + red[256 + tid] + red[512 + tid] + red[768 + tid] + avb[0];
                float ev = __expf(sc);
                es_l[tid] = ev;
                if (eq == 0) esb[b*S_ + sp*256 + tid] = ev;
            }
            __syncthreads();
            if (tid < 32){
                float d = 0.f;
                #pragma unroll
                for (int i = 0; i < 8; ++i) d += es_l[tid*8 + i];
                red[tid] = d;
            }
            __syncthreads();
            if (tid == 0 && eq == 0){
                float d = 0.f;
                #pragma unroll
                for (int i = 0; i < 32; ++i) d += red[i];
                denp[sp*32 + b] = d;
            }
            __syncthreads();
            // context partials: 128 e's for this eq, over this sp's 256 s
            const int sgr = tid >> 7, el = tid & 127;
            const int eg = eq*128 + el;
            const float* eb = enc + ((size_t)(b*S_ + sp*256 + sgr*32))*ENC_ + eg;
            float ca = 0.f;
            #pragma unroll 4
            for (int i = 0; i < 32; ++i)
                ca += es_l[sgr*32 + i] * eb[(size_t)i*ENC_];
            red[tid] = ca;
            __syncthreads();
            if (tid < 128){
                float c = 0.f;
                #pragma unroll
                for (int i = 0; i < 8; ++i) c += red[i*128 + tid];
                ctxp[sp*(B_*ENC_) + b*ENC_ + eq*128 + tid] = c;
            }
        }
        grid.sync();

        // ================= PHASE Z =================
        {
            const int b = tid >> 5, kl = tid & 31;
            const float* wC = wic_s + (size_t)bid*(512*12);
            const float* c0p = ctxp + b*ENC_;
            const float* c1p = ctxp + 16384 + b*ENC_;
            float acc[12];
            #pragma unroll
            for (int j = 0; j < 12; ++j) acc[j] = 0.f;
            for (int q = 0; q < 16; ++q){
                int e = q*32 + kl;
                float cv = c0p[e] + c1p[e];
                const float* w = wC + e*12;
                #pragma unroll
                for (int j = 0; j < 12; j += 4){
                    float4 wv = *(const float4*)(w + j);
                    acc[j]   += cv*wv.x; acc[j+1] += cv*wv.y;
                    acc[j+2] += cv*wv.z; acc[j+3] += cv*wv.w;
                }
            }
            #pragma unroll
            for (int m = 1; m <= 16; m <<= 1){
                #pragma unroll
                for (int j = 0; j < 12; ++j) acc[j] += __shfl_xor(acc[j], m);
            }
            float* gic_l = smem;  // [32][12]
            if (kl == 0){
                float rden = frcp(denp[b] + denp[32 + b]);
                #pragma unroll
                for (int j = 0; j < 12; ++j) gic_l[b*12 + j] = acc[j]*rden;
            }
            __syncthreads();
            if (tid < 128){
                const int bb = tid >> 2, dd = tid & 3;
                const int d = bid*4 + dd;
                const float* gx = gixb + bb*G3_;
                const float* gg = ghb  + bb*G3_;
                float gir = gx[d]        + gic_l[bb*12 + dd]     + bih[d];
                float ghr = gg[d]        + bhh[d];
                float giz = gx[1024 + d] + gic_l[bb*12 + 4 + dd] + bih[1024 + d];
                float ghz = gg[1024 + d] + bhh[1024 + d];
                float gin = gx[2048 + d] + gic_l[bb*12 + 8 + dd] + bih[2048 + d];
                float ghn = gg[2048 + d] + bhh[2048 + d];
                float r  = fsig(gir + ghr);
                float zf = fsig(giz + ghz);
                float nn = ftanh(gin + r*ghn);
                hn[bb*DEC_ + d] = (1.f - zf)*nn + zf*hp[bb*DEC_ + d];
            } else if (tid < 192){
                const int i = tid - 128;
                const int flat = bid*64 + i;
                const int bb = flat >> 9, s = flat & 511;
                float rden = frcp(denp[bb] + denp[32 + bb]);
                out[AW_OFF + ((size_t)bb*T_ + t)*S_ + s] = esb[bb*S_ + s]*rden;
            }
        }
        grid.sync();
    }
}

extern "C" void kernel_launch(void* const* d_in, const int* in_sizes, int n_in,
                              void* d_out, int out_size, void* d_ws, size_t ws_size,
                              hipStream_t stream){
    const float* enc = (const float*)d_in[0];
    const float* tm  = (const float*)d_in[1];
    const float* pw1 = (const float*)d_in[2];
    const float* pb1 = (const float*)d_in[3];
    const float* pw2 = (const float*)d_in[4];
    const float* pb2 = (const float*)d_in[5];
    const float* awe = (const float*)d_in[6];
    const float* abe = (const float*)d_in[7];
    const float* awd = (const float*)d_in[8];
    const float* abd = (const float*)d_in[9];
    const float* av  = (const float*)d_in[10];
    const float* avb = (const float*)d_in[11];
    const float* wih = (const float*)d_in[12];
    const float* whh = (const float*)d_in[13];
    const float* bih = (const float*)d_in[14];
    const float* bhh = (const float*)d_in[15];
    const float* oww = (const float*)d_in[16];
    const float* obb = (const float*)d_in[17];
    const float* sww = (const float*)d_in[18];
    const float* sbb = (const float*)d_in[19];
    float* out = (float*)d_out;
    float* ws  = (float*)d_ws;

    // workspace layout (floats) — total ~45.6 MB
    float* whh_s = ws;                    // 3,145,728
    float* wix_s = whh_s + 3145728;       //   786,432
    float* wic_s = wix_s + 786432;        // 1,572,864
    float* wd_s  = wic_s + 1572864;       //   131,072
    float* ow_s  = wd_s  + 131072;        //   196,608
    float* xall  = ow_s  + 196608;        // 4,194,304
    float* hbuf  = xall  + 4194304;       //    65,536
    float* ghb   = hbuf  + 65536;         //    98,304
    float* gixb  = ghb   + 98304;         //    98,304
    float* dproj = gixb  + 98304;         //     4,096
    float* esb   = dproj + 4096;          //    16,384
    float* denp  = esb   + 16384;         //        64
    float* ctxp  = denp  + 64;            //    32,768
    __hip_bfloat16* ep = (__hip_bfloat16*)(ctxp + 32768);  // 2,097,152 bf16

    hipMemsetAsync(hbuf, 0, (size_t)65536*sizeof(float), stream);

    k_prep<<<22784, 256, 0, stream>>>(whh, wih, awd, oww,
                                      whh_s, wix_s, wic_s, wd_s, ow_s);
    k_encproj<<<512, 128, 0, stream>>>(enc, awe, abe, ep);
    k_prenet<<<1024, 128, 0, stream>>>(tm, pw1, pb1, pw2, pb2, xall);

    const float* a_enc = enc; const float* a_xall = xall;
    const __hip_bfloat16* a_ep = ep;
    const float* a_whh_s = whh_s; const float* a_wix_s = wix_s;
    const float* a_wic_s = wic_s; const float* a_wd_s = wd_s;
    const float* a_ow_s = ow_s;  const float* a_sw = sww;
    const float* a_bd = abd;     const float* a_av = av;
    const float* a_avb = avb;    const float* a_bih = bih;
    const float* a_bhh = bhh;    const float* a_ob = obb;
    const float* a_sb = sbb;
    float* a_hbuf = hbuf; float* a_ghb = ghb; float* a_gixb = gixb;
    float* a_dproj = dproj; float* a_esb = esb; float* a_denp = denp;
    float* a_ctxp = ctxp; float* a_out = out;

    void* args[] = {
        (void*)&a_enc, (void*)&a_xall, (void*)&a_ep,
        (void*)&a_whh_s, (void*)&a_wix_s, (void*)&a_wic_s,
        (void*)&a_wd_s, (void*)&a_ow_s, (void*)&a_sw,
        (void*)&a_bd, (void*)&a_av, (void*)&a_avb,
        (void*)&a_bih, (void*)&a_bhh, (void*)&a_ob, (void*)&a_sb,
        (void*)&a_hbuf, (void*)&a_ghb, (void*)&a_gixb,
        (void*)&a_dproj, (void*)&a_esb, (void*)&a_denp,
        (void*)&a_ctxp, (void*)&a_out
    };
    hipLaunchCooperativeKernel((void*)k_persist, dim3(256), dim3(1024),
                               args, 0, stream);
}

// Round 3
// 85366.412 us; speedup vs baseline: 1.1751x; 1.1751x over previous
//
#include <hip/hip_runtime.h>
#include <hip/hip_bf16.h>

// Problem constants
constexpr int B_   = 32;
constexpr int S_   = 512;
constexpr int T_   = 512;
constexpr int ENC_ = 512;
constexpr int ATT_ = 128;
constexpr int PO_  = 256;
constexpr int DEC_ = 1024;
constexpr int M_   = 128;
constexpr int G3_  = 3072;   // 3*DEC

// Output offsets (floats)
constexpr int MEL_OFF  = 0;
constexpr int STOP_OFF = B_*T_*M_;            // 2,097,152
constexpr int AW_OFF   = STOP_OFF + B_*T_;    // 2,113,536

__device__ __forceinline__ float frcp(float x){ return __builtin_amdgcn_rcpf(x); }
__device__ __forceinline__ float ftanh(float x){
    float e = __expf(2.0f*x);
    return 1.0f - 2.0f*frcp(e + 1.0f);
}
__device__ __forceinline__ float fsig(float x){ return frcp(1.0f + __expf(-x)); }

// ---- agent-scope (device-coherent, L2-bypassing) accessors -------------------
__device__ __forceinline__ float ald(const float* p){
    return __hip_atomic_load(p, __ATOMIC_RELAXED, __HIP_MEMORY_SCOPE_AGENT);
}
__device__ __forceinline__ void ast(float* p, float v){
    __hip_atomic_store(p, v, __ATOMIC_RELAXED, __HIP_MEMORY_SCOPE_AGENT);
}
union F2U { float2 f; unsigned long long u; };
__device__ __forceinline__ void ast2(float* p, float a, float b){
    F2U x; x.f = make_float2(a, b);
    __hip_atomic_store((unsigned long long*)p, x.u, __ATOMIC_RELAXED, __HIP_MEMORY_SCOPE_AGENT);
}
__device__ __forceinline__ float2 ald2(const float* p){
    F2U x; x.u = __hip_atomic_load((const unsigned long long*)p, __ATOMIC_RELAXED, __HIP_MEMORY_SCOPE_AGENT);
    return x.f;
}

// ---- grid barrier: no cache flush/invalidate; relaxed agent atomics ----------
__device__ __forceinline__ void gbar(unsigned int* cnt, unsigned int target){
    asm volatile("s_waitcnt vmcnt(0) lgkmcnt(0)" ::: "memory");
    __syncthreads();
    if (threadIdx.x == 0){
        __hip_atomic_fetch_add(cnt, 1u, __ATOMIC_RELAXED, __HIP_MEMORY_SCOPE_AGENT);
        while (__hip_atomic_load(cnt, __ATOMIC_RELAXED, __HIP_MEMORY_SCOPE_AGENT) < target){
            __builtin_amdgcn_s_sleep(1);
        }
    }
    __syncthreads();
}

// ---------------- prep: swizzled weight slabs ---------------------------------
// whh_s2[gb 192][kk 512][jj 32] = whh[( (gb>>1)*32 + jj )*1024 + (gb&1)*512 + kk]
// wix_s2[g 96][kk 256][jj 32]   = wih[(g*32 + jj)*768 + kk]
// wic_z [ds 64][jj 48][e 512]   = wih[((jj>>4)*1024 + ds*16 + (jj&15))*768 + 256 + e]
// ow_s  [i 16][k 1536][j 8]     = oww[k*128 + i*8 + j]
__global__ __launch_bounds__(256) void k_prep(const float* __restrict__ whh,
        const float* __restrict__ wih, const float* __restrict__ oww,
        float* __restrict__ whh_s2, float* __restrict__ wix_s2,
        float* __restrict__ wic_z, float* __restrict__ ow_s){
    long long idx = (long long)blockIdx.x*256 + threadIdx.x;
    if (idx < 3145728LL){
        int gb = (int)(idx >> 14); int rr = (int)(idx & 16383);
        int kk = rr >> 5, jj = rr & 31;
        whh_s2[idx] = whh[(size_t)((gb >> 1)*32 + jj)*1024 + (gb & 1)*512 + kk];
    } else if (idx < 3932160LL){
        long long q = idx - 3145728LL;
        int g = (int)(q >> 13); int rr = (int)(q & 8191);
        int kk = rr >> 5, jj = rr & 31;
        wix_s2[q] = wih[(size_t)(g*32 + jj)*768 + kk];
    } else if (idx < 5505024LL){
        long long q = idx - 3932160LL;
        int ds = (int)(q / 24576); int rr = (int)(q % 24576);
        int jj = rr >> 9, e = rr & 511;
        wic_z[q] = wih[(size_t)((jj >> 4)*1024 + ds*16 + (jj & 15))*768 + 256 + e];
    } else if (idx < 5701632LL){
        long long q = idx - 5505024LL;
        int i = (int)(q / 12288); int rr = (int)(q % 12288);
        int k = rr >> 3, j = rr & 7;
        ow_s[q] = oww[(size_t)k*128 + i*8 + j];
    }
}

// ---------------- prep: ep[b][a][s] = bf16(enc @ att_we + be) -----------------
__global__ __launch_bounds__(128) void k_encproj(const float* __restrict__ enc,
        const float* __restrict__ we, const float* __restrict__ be,
        __hip_bfloat16* __restrict__ ep_t){
    __shared__ float wel[64*128];
    __shared__ float encl[32*69];
    int b = blockIdx.x >> 4, s0 = (blockIdx.x & 15) << 5;
    int tid = threadIdx.x;
    int sl = tid & 31, ag = tid >> 5;
    float acc[32];
    #pragma unroll
    for (int i = 0; i < 32; i++) acc[i] = 0.f;
    for (int k0 = 0; k0 < ENC_; k0 += 64){
        __syncthreads();
        for (int p = 0; p < 64; p++){
            int idx = tid + (p << 7);
            wel[idx] = we[(size_t)(k0 + (idx >> 7))*ATT_ + (idx & 127)];
        }
        for (int p = 0; p < 16; p++){
            int idx = tid + (p << 7);
            int kk = idx & 63, ss = idx >> 6;
            encl[ss*69 + kk] = enc[((size_t)b*S_ + s0 + ss)*ENC_ + k0 + kk];
        }
        __syncthreads();
        for (int kk = 0; kk < 64; kk++){
            float ev = encl[sl*69 + kk];
            const float* wr = &wel[(kk << 7) + (ag << 5)];
            #pragma unroll
            for (int j = 0; j < 32; j++) acc[j] += ev * wr[j];
        }
    }
    #pragma unroll
    for (int j = 0; j < 32; j++){
        int a = (ag << 5) + j;
        ep_t[((size_t)b*ATT_ + a)*S_ + s0 + sl] = __float2bfloat16(acc[j] + be[a]);
    }
}

// ---------------- prep: X_all[t][b][:] = PreNet(prev_mel) ---------------------
__global__ __launch_bounds__(128) void k_prenet(const float* __restrict__ tm,
        const float* __restrict__ w1, const float* __restrict__ b1,
        const float* __restrict__ w2, const float* __restrict__ b2,
        float* __restrict__ xall){
    __shared__ float mel_l[128*20];
    __shared__ float h1_l[256*20];
    int row0 = blockIdx.x << 4;
    int t = row0 >> 5, b0 = row0 & 31;
    int tid = threadIdx.x;
    for (int p = 0; p < 16; p++){
        int idx = tid + (p << 7);
        int k = idx & 127, r = idx >> 7;
        float v = 0.f;
        if (t > 0) v = tm[((size_t)(b0 + r)*T_ + (t - 1))*M_ + k];
        mel_l[k*20 + r] = v;
    }
    __syncthreads();
    float acc1[16], acc2[16];
    #pragma unroll
    for (int i = 0; i < 16; i++){ acc1[i] = 0.f; acc2[i] = 0.f; }
    for (int k = 0; k < M_; k++){
        float wa = w1[k*256 + tid];
        float wb = w1[k*256 + tid + 128];
        float mv[16];
        *(float4*)&mv[0]  = *(const float4*)&mel_l[k*20 + 0];
        *(float4*)&mv[4]  = *(const float4*)&mel_l[k*20 + 4];
        *(float4*)&mv[8]  = *(const float4*)&mel_l[k*20 + 8];
        *(float4*)&mv[12] = *(const float4*)&mel_l[k*20 + 12];
        #pragma unroll
        for (int r = 0; r < 16; r++){ acc1[r] += mv[r]*wa; acc2[r] += mv[r]*wb; }
    }
    float bb1a = b1[tid], bb1b = b1[tid + 128];
    #pragma unroll
    for (int r = 0; r < 16; r++){
        h1_l[tid*20 + r]         = fmaxf(acc1[r] + bb1a, 0.f);
        h1_l[(tid + 128)*20 + r] = fmaxf(acc2[r] + bb1b, 0.f);
    }
    __syncthreads();
    #pragma unroll
    for (int i = 0; i < 16; i++){ acc1[i] = 0.f; acc2[i] = 0.f; }
    for (int k = 0; k < 256; k++){
        float wa = w2[k*256 + tid];
        float wb = w2[k*256 + tid + 128];
        float mv[16];
        *(float4*)&mv[0]  = *(const float4*)&h1_l[k*20 + 0];
        *(float4*)&mv[4]  = *(const float4*)&h1_l[k*20 + 4];
        *(float4*)&mv[8]  = *(const float4*)&h1_l[k*20 + 8];
        *(float4*)&mv[12] = *(const float4*)&h1_l[k*20 + 12];
        #pragma unroll
        for (int r = 0; r < 16; r++){ acc1[r] += mv[r]*wa; acc2[r] += mv[r]*wb; }
    }
    float bb2a = b2[tid], bb2b = b2[tid + 128];
    #pragma unroll
    for (int r = 0; r < 16; r++){
        xall[((size_t)row0 + r)*PO_ + tid]       = fmaxf(acc1[r] + bb2a, 0.f);
        xall[((size_t)row0 + r)*PO_ + tid + 128] = fmaxf(acc2[r] + bb2b, 0.f);
    }
}

// ---------------- mel/stop for step tm1 = t-1 (16 blocks: bid 192..207) -------
__device__ __forceinline__ void mel_part(int t, int i, int tid,
        const float* hbuf, const float* ctxp2, const float* denp2,
        const float* ow_s, const float* sw, const float* ob, const float* sb,
        float* out){
    const int b = tid >> 5, kl = tid & 31;
    const int par = (t - 1) & 1;
    const float* hr = hbuf + (t & 1)*(B_*DEC_) + b*DEC_;
    const float rden = frcp(ald(&denp2[(par*2 + 0)*B_ + b]) +
                            ald(&denp2[(par*2 + 1)*B_ + b]));
    const float* wO = ow_s + (size_t)i*(1536*8);
    float acc[8];
    #pragma unroll
    for (int j = 0; j < 8; ++j) acc[j] = 0.f;
    float sacc = 0.f;
    for (int q = 0; q < 32; ++q){
        int k = q*32 + kl;
        float dv = ald(&hr[k]);
        const float* w = wO + (size_t)k*8;
        #pragma unroll
        for (int j = 0; j < 8; j += 4){
            float4 wv = *(const float4*)(w + j);
            acc[j]   += dv*wv.x; acc[j+1] += dv*wv.y;
            acc[j+2] += dv*wv.z; acc[j+3] += dv*wv.w;
        }
        if (i == 15) sacc += dv*sw[k];
    }
    for (int q = 0; q < 16; ++q){
        int e = q*32 + kl;
        int k = 1024 + e;
        float dv = (ald(&ctxp2[((par*2 + 0)*B_ + b)*ENC_ + e]) +
                    ald(&ctxp2[((par*2 + 1)*B_ + b)*ENC_ + e]))*rden;
        const float* w = wO + (size_t)k*8;
        #pragma unroll
        for (int j = 0; j < 8; j += 4){
            float4 wv = *(const float4*)(w + j);
            acc[j]   += dv*wv.x; acc[j+1] += dv*wv.y;
            acc[j+2] += dv*wv.z; acc[j+3] += dv*wv.w;
        }
        if (i == 15) sacc += dv*sw[k];
    }
    #pragma unroll
    for (int m = 1; m <= 16; m <<= 1){
        #pragma unroll
        for (int j = 0; j < 8; ++j) acc[j] += __shfl_xor(acc[j], m);
        if (i == 15) sacc += __shfl_xor(sacc, m);
    }
    if (kl == 0){
        float* mo = out + MEL_OFF + ((size_t)b*T_ + (t - 1))*M_ + i*8;
        #pragma unroll
        for (int j = 0; j < 8; ++j) mo[j] = acc[j] + ob[i*8 + j];
        if (i == 15) out[STOP_OFF + b*T_ + (t - 1)] = sacc + sb[0];
    }
}

// ---------------- the persistent decoder loop ---------------------------------
// 256 blocks x 1024 threads, cooperative residency, custom no-flush barriers.
__global__ __launch_bounds__(1024, 4) void k_persist(
    const float* __restrict__ enc,        // [32][512][512]
    const float* __restrict__ xall,       // [T*32][256]
    const __hip_bfloat16* __restrict__ ep,// [32][128][512]
    const float* __restrict__ whh_s2,     // [192][512][32]
    const float* __restrict__ wix_s2,     // [96][256][32]
    const float* __restrict__ wic_z,      // [64][48][512]
    const float* __restrict__ awd,        // [1024][128]
    const float* __restrict__ ow_s,       // [16][1536][8]
    const float* __restrict__ sw,         // [1536]
    const float* __restrict__ bd,         // [128]
    const float* __restrict__ av,         // [128]
    const float* __restrict__ avb,        // [1]
    const float* __restrict__ bih,        // [3072]
    const float* __restrict__ bhh,        // [3072]
    const float* __restrict__ ob,         // [128]
    const float* __restrict__ sb,         // [1]
    float* __restrict__ hbuf,             // [2][32][1024]
    float* __restrict__ ghp,              // [2 kh][32][3072]
    float* __restrict__ gixp,             // [32][3072]
    float* __restrict__ dpp,              // [64 ds][32][128]
    float* __restrict__ esb,              // [32][512]
    float* __restrict__ denp2,            // [2 par][2 sp][32]
    float* __restrict__ ctxp2,            // [2 par][2 sp][32][512]
    unsigned int* __restrict__ cnt,       // barrier counter
    float* __restrict__ out)
{
    extern __shared__ float lds_enc[];    // [256 s][128 e] this block's slice
    __shared__ float smem[4640];
    const int bid = blockIdx.x, tid = threadIdx.x;

    // role mappings (XCD-affine via bid&7; perf heuristic only)
    const int x8 = bid & 7, r5 = bid >> 3;
    const int yb = x8*4 + (r5 & 3), ysp = (r5 >> 2) & 1, yeq = (r5 >> 3) & 3;
    const int zds = x8*8 + ((bid >> 3) & 7), zbg = bid >> 6;

    // preload enc slice into LDS (once)
    for (int i = tid; i < 32768; i += 1024){
        int s = i >> 7, e = i & 127;
        lds_enc[i] = enc[((size_t)yb*S_ + ysp*256 + s)*ENC_ + yeq*128 + e];
    }
    __syncthreads();

    unsigned int epoch = 0;

    for (int t = 0; t < T_; ++t){
        const int par = t & 1;
        const float* hp = hbuf + (size_t)par*(B_*DEC_);
        float*       hn = hbuf + (size_t)(par ^ 1)*(B_*DEC_);

        // ================= PHASE 1: attention + gh/gix GEMM + mel(t-1) =======
        {   // ---- attention (all 256 blocks: (yb, ysp, yeq)) ----
            float* red  = smem;          // [1024]
            float* es_l = smem + 1024;   // [256]
            float* dpl  = smem + 1280;   // [128]
            float* vl   = smem + 1408;   // [128]
            {   // dp = bd + sum over 64 dp-partials (from Z(t-1))
                int a = tid & 127, g = tid >> 7;         // g<8
                float dp = 0.f;
                #pragma unroll
                for (int s8 = 0; s8 < 8; ++s8)
                    dp += ald(&dpp[((g*8 + s8)*B_ + yb)*ATT_ + a]);
                red[tid] = dp;
            }
            __syncthreads();
            if (tid < 128){
                float dp = bd[tid];
                #pragma unroll
                for (int g = 0; g < 8; ++g) dp += red[g*128 + tid];
                dpl[tid] = dp; vl[tid] = av[tid];
            }
            __syncthreads();
            // scores (redundant across yeq) for this sp-half's 256 s
            const int ag = tid >> 8, sl_ = tid & 255;
            const int sg = ysp*256 + sl_;
            const __hip_bfloat16* epb = ep + ((size_t)(yb*ATT_ + ag*32))*S_ + sg;
            float acc = 0.f;
            #pragma unroll 4
            for (int aa = 0; aa < 32; ++aa){
                float e = __bfloat162float(epb[(size_t)aa*S_]);
                int a = ag*32 + aa;
                acc += ftanh(e + dpl[a]) * vl[a];
            }
            red[tid] = acc;
            __syncthreads();
            if (tid < 256){
                float sc = red[tid] + red[256+tid] + red[512+tid] + red[768+tid] + avb[0];
                float ev = __expf(sc);
                es_l[tid] = ev;
                if (yeq == 0) ast(&esb[yb*S_ + ysp*256 + tid], ev);
            }
            __syncthreads();
            if (tid < 32){
                float d = 0.f;
                #pragma unroll
                for (int i = 0; i < 8; ++i) d += es_l[tid*8 + i];
                red[tid] = d;
            }
            __syncthreads();
            if (tid == 0 && yeq == 0){
                float d = 0.f;
                #pragma unroll
                for (int i = 0; i < 32; ++i) d += red[i];
                ast(&denp2[(par*2 + ysp)*B_ + yb], d);
            }
            __syncthreads();
            // ctx partials from LDS enc slice: 128 e for this yeq, 256 s
            const int sgr = tid >> 7, el = tid & 127;
            float ca = 0.f;
            #pragma unroll 4
            for (int i = 0; i < 32; ++i)
                ca += es_l[sgr*32 + i] * lds_enc[(sgr*32 + i)*128 + el];
            red[tid] = ca;
            __syncthreads();
            if (tid < 128){
                float c = 0.f;
                #pragma unroll
                for (int i = 0; i < 8; ++i) c += red[i*128 + tid];
                ast(&ctxp2[((par*2 + ysp)*B_ + yb)*ENC_ + yeq*128 + tid], c);
            }
            __syncthreads();
        }
        if (bid < 192){
            // ---- gh = h @ Whh^T (32 j, k-half), gix for kh==0 blocks ----
            const int jslice = bid >> 1, kh = bid & 1;
            const int j0 = jslice*32;
            const int b = tid >> 5, kl = tid & 31;
            const float* hr = hp + b*DEC_ + kh*512;
            const float* wH = whh_s2 + (size_t)bid*(512*32);
            float hv[16];
            #pragma unroll
            for (int q = 0; q < 16; ++q) hv[q] = ald(&hr[q*32 + kl]);
            float acc[32];
            #pragma unroll
            for (int j = 0; j < 32; ++j) acc[j] = 0.f;
            for (int q = 0; q < 16; ++q){
                int k = q*32 + kl;
                const float* w = wH + (size_t)k*32;
                float h_ = hv[q];
                #pragma unroll
                for (int j = 0; j < 32; j += 4){
                    float4 wv = *(const float4*)(w + j);
                    acc[j]   += h_*wv.x; acc[j+1] += h_*wv.y;
                    acc[j+2] += h_*wv.z; acc[j+3] += h_*wv.w;
                }
            }
            #pragma unroll
            for (int m = 1; m <= 16; m <<= 1){
                #pragma unroll
                for (int j = 0; j < 32; ++j) acc[j] += __shfl_xor(acc[j], m);
            }
            if (kl == 0){
                float* go = ghp + (size_t)kh*(B_*G3_) + b*G3_ + j0;
                #pragma unroll
                for (int j = 0; j < 32; j += 2) ast2(&go[j], acc[j], acc[j+1]);
            }
            if (kh == 0){
                const float* xr = xall + ((size_t)t*B_ + b)*PO_;
                const float* wX = wix_s2 + (size_t)jslice*(256*32);
                float xv[8];
                #pragma unroll
                for (int q = 0; q < 8; ++q) xv[q] = xr[q*32 + kl];
                #pragma unroll
                for (int j = 0; j < 32; ++j) acc[j] = 0.f;
                for (int q = 0; q < 8; ++q){
                    int k = q*32 + kl;
                    const float* w = wX + (size_t)k*32;
                    float x_ = xv[q];
                    #pragma unroll
                    for (int j = 0; j < 32; j += 4){
                        float4 wv = *(const float4*)(w + j);
                        acc[j]   += x_*wv.x; acc[j+1] += x_*wv.y;
                        acc[j+2] += x_*wv.z; acc[j+3] += x_*wv.w;
                    }
                }
                #pragma unroll
                for (int m = 1; m <= 16; m <<= 1){
                    #pragma unroll
                    for (int j = 0; j < 32; ++j) acc[j] += __shfl_xor(acc[j], m);
                }
                if (kl == 0){
                    float* xo = gixp + b*G3_ + j0;
                    #pragma unroll
                    for (int j = 0; j < 32; j += 2) ast2(&xo[j], acc[j], acc[j+1]);
                }
            }
        } else if (bid < 208 && t >= 1){
            mel_part(t, bid - 192, tid, hbuf, ctxp2, denp2, ow_s, sw, ob, sb, out);
        }
        gbar(cnt, (++epoch)*256u);

        // ================= PHASE 2: gic + gates -> h(t+1), dp-partials, aw ====
        {
            float* ctx_s  = smem;          // [8][512]
            float* rden_s = smem + 4096;   // [8]
            float* gic_s  = smem + 4104;   // [384]
            float* h_l    = smem + 4488;   // [128]
            for (int i = tid; i < 4096; i += 1024){
                int bb = i >> 9, e = i & 511;
                int b = zbg*8 + bb;
                float c0 = ald(&ctxp2[((par*2 + 0)*B_ + b)*ENC_ + e]);
                float c1 = ald(&ctxp2[((par*2 + 1)*B_ + b)*ENC_ + e]);
                ctx_s[bb*512 + e] = c0 + c1;
            }
            if (tid < 8){
                int b = zbg*8 + tid;
                rden_s[tid] = frcp(ald(&denp2[(par*2 + 0)*B_ + b]) +
                                   ald(&denp2[(par*2 + 1)*B_ + b]));
            }
            __syncthreads();
            if (tid < 768){
                int o = tid >> 1, eh = tid & 1;        // o = bb*48 + jj
                int bb = o / 48, jj = o - bb*48;
                const float* wr = wic_z + ((size_t)zds*48 + jj)*512 + eh*256;
                const float* cr = ctx_s + bb*512 + eh*256;
                float a = 0.f;
                for (int e = 0; e < 256; e += 4){
                    float4 wv = *(const float4*)(wr + e);
                    float4 cv = *(const float4*)(cr + e);
                    a += wv.x*cv.x + wv.y*cv.y + wv.z*cv.z + wv.w*cv.w;
                }
                a += __shfl_xor(a, 1);
                if (eh == 0) gic_s[o] = a * rden_s[bb];
            }
            __syncthreads();
            if (tid < 128){
                int bb = tid >> 4, dloc = tid & 15;
                int b = zbg*8 + bb;
                int d = zds*16 + dloc;
                float gxr = ald(&gixp[b*G3_ + d]);
                float gxz = ald(&gixp[b*G3_ + 1024 + d]);
                float gxn = ald(&gixp[b*G3_ + 2048 + d]);
                float ghr = ald(&ghp[b*G3_ + d])        + ald(&ghp[B_*G3_ + b*G3_ + d]);
                float ghz = ald(&ghp[b*G3_ + 1024 + d]) + ald(&ghp[B_*G3_ + b*G3_ + 1024 + d]);
                float ghn = ald(&ghp[b*G3_ + 2048 + d]) + ald(&ghp[B_*G3_ + b*G3_ + 2048 + d]);
                float gir = gxr + gic_s[bb*48 + dloc]      + bih[d];
                float giz = gxz + gic_s[bb*48 + 16 + dloc] + bih[1024 + d];
                float gin = gxn + gic_s[bb*48 + 32 + dloc] + bih[2048 + d];
                float Ghr = ghr + bhh[d];
                float Ghz = ghz + bhh[1024 + d];
                float Ghn = ghn + bhh[2048 + d];
                float rr = fsig(gir + Ghr);
                float zz = fsig(giz + Ghz);
                float nn = ftanh(gin + rr*Ghn);
                float hv = (1.f - zz)*nn + zz*ald(&hp[b*DEC_ + d]);
                ast(&hn[b*DEC_ + d], hv);
                h_l[bb*16 + dloc] = hv;
            } else if (tid < 192){
                int i = tid - 128;
                int flat = bid*64 + i;
                int bb2 = flat >> 9, s = flat & 511;
                float rd = frcp(ald(&denp2[(par*2 + 0)*B_ + bb2]) +
                                ald(&denp2[(par*2 + 1)*B_ + bb2]));
                out[AW_OFF + ((size_t)bb2*T_ + t)*S_ + s] = ald(&esb[bb2*S_ + s])*rd;
            }
            __syncthreads();
            {   // dp-partials for step t+1: dpp[zds][b][a] over this block's 16 d
                int bb = tid >> 7, a = tid & 127;
                int b = zbg*8 + bb;
                float dpa = 0.f;
                #pragma unroll
                for (int dl = 0; dl < 16; ++dl)
                    dpa += h_l[bb*16 + dl] * awd[(size_t)(zds*16 + dl)*ATT_ + a];
                ast(&dpp[(zds*B_ + b)*ATT_ + a], dpa);
            }
        }
        gbar(cnt, (++epoch)*256u);
    }
    // tail: mel/stop for t-1 = T_-1
    if (bid >= 192 && bid < 208){
        mel_part(T_, bid - 192, tid, hbuf, ctxp2, denp2, ow_s, sw, ob, sb, out);
    }
}

extern "C" void kernel_launch(void* const* d_in, const int* in_sizes, int n_in,
                              void* d_out, int out_size, void* d_ws, size_t ws_size,
                              hipStream_t stream){
    const float* enc = (const float*)d_in[0];
    const float* tm  = (const float*)d_in[1];
    const float* pw1 = (const float*)d_in[2];
    const float* pb1 = (const float*)d_in[3];
    const float* pw2 = (const float*)d_in[4];
    const float* pb2 = (const float*)d_in[5];
    const float* awe = (const float*)d_in[6];
    const float* abe = (const float*)d_in[7];
    const float* awd = (const float*)d_in[8];
    const float* abd = (const float*)d_in[9];
    const float* av  = (const float*)d_in[10];
    const float* avb = (const float*)d_in[11];
    const float* wih = (const float*)d_in[12];
    const float* whh = (const float*)d_in[13];
    const float* bih = (const float*)d_in[14];
    const float* bhh = (const float*)d_in[15];
    const float* oww = (const float*)d_in[16];
    const float* obb = (const float*)d_in[17];
    const float* sww = (const float*)d_in[18];
    const float* sbb = (const float*)d_in[19];
    float* out = (float*)d_out;
    float* ws  = (float*)d_ws;

    // workspace layout (float slots)
    float* whh_s2 = ws;                     // 3,145,728
    float* wix_s2 = whh_s2 + 3145728;       //   786,432
    float* wic_z  = wix_s2 + 786432;        // 1,572,864
    float* ow_s   = wic_z  + 1572864;       //   196,608
    float* xall   = ow_s   + 196608;        // 4,194,304
    float* hbuf   = xall   + 4194304;       //    65,536
    float* ghp    = hbuf   + 65536;         //   196,608
    float* gixp   = ghp    + 196608;        //    98,304
    float* dpp    = gixp   + 98304;         //   262,144
    float* esb    = dpp    + 262144;        //    16,384
    float* denp2  = esb    + 16384;         //       128
    float* ctxp2  = denp2  + 128;           //    65,536
    unsigned int* cnt = (unsigned int*)(ctxp2 + 65536);   // 16 slots
    __hip_bfloat16* ep = (__hip_bfloat16*)(ctxp2 + 65536 + 16); // 1,048,576 slots

    hipMemsetAsync(hbuf, 0, (size_t)65536*sizeof(float), stream);
    hipMemsetAsync(dpp, 0, (size_t)262144*sizeof(float), stream);
    hipMemsetAsync(cnt, 0, 64, stream);

    k_prep<<<22272, 256, 0, stream>>>(whh, wih, oww, whh_s2, wix_s2, wic_z, ow_s);
    k_encproj<<<512, 128, 0, stream>>>(enc, awe, abe, ep);
    k_prenet<<<1024, 128, 0, stream>>>(tm, pw1, pb1, pw2, pb2, xall);

    hipFuncSetAttribute((const void*)k_persist,
                        hipFuncAttributeMaxDynamicSharedMemorySize, 131072);

    const float* a_enc = enc; const float* a_xall = xall;
    const __hip_bfloat16* a_ep = ep;
    const float* a_whh = whh_s2; const float* a_wix = wix_s2;
    const float* a_wic = wic_z;  const float* a_awd = awd;
    const float* a_ow = ow_s;    const float* a_sw = sww;
    const float* a_bd = abd;     const float* a_av = av;
    const float* a_avb = avb;    const float* a_bih = bih;
    const float* a_bhh = bhh;    const float* a_ob = obb;
    const float* a_sb = sbb;
    float* a_hbuf = hbuf; float* a_ghp = ghp; float* a_gixp = gixp;
    float* a_dpp = dpp; float* a_esb = esb; float* a_denp2 = denp2;
    float* a_ctxp2 = ctxp2; unsigned int* a_cnt = cnt; float* a_out = out;

    void* args[] = {
        (void*)&a_enc, (void*)&a_xall, (void*)&a_ep,
        (void*)&a_whh, (void*)&a_wix, (void*)&a_wic, (void*)&a_awd,
        (void*)&a_ow, (void*)&a_sw, (void*)&a_bd, (void*)&a_av, (void*)&a_avb,
        (void*)&a_bih, (void*)&a_bhh, (void*)&a_ob, (void*)&a_sb,
        (void*)&a_hbuf, (void*)&a_ghp, (void*)&a_gixp, (void*)&a_dpp,
        (void*)&a_esb, (void*)&a_denp2, (void*)&a_ctxp2, (void*)&a_cnt,
        (void*)&a_out
    };
    hipLaunchCooperativeKernel((void*)k_persist, dim3(256), dim3(1024),
                               args, 131072, stream);
}